// Round 12
// baseline (439.943 us; speedup 1.0000x reference)
//
#include <hip/hip_runtime.h>
#include <hip/hip_bf16.h>

#define CC 192

typedef __attribute__((ext_vector_type(8))) short bf16x8;
typedef __attribute__((ext_vector_type(4))) float f32x4;

__device__ __forceinline__ unsigned short f2bf(float f) {
    unsigned int u = __float_as_uint(f);
    u = (u + 0x7fffu + ((u >> 16) & 1u)) >> 16;
    return (unsigned short)u;
}

__device__ __forceinline__ f32x4 mfma16(bf16x8 a, bf16x8 b, f32x4 c) {
    return __builtin_amdgcn_mfma_f32_16x16x32_bf16(a, b, c, 0, 0, 0);
}

// Merged prep: 4 weight transposes (f32 [K][N] -> bf16 [N][K]) + bias expand.
__global__ void k_prep(const float* __restrict__ qkv_w, const float* __restrict__ proj_w,
                       const float* __restrict__ w1, const float* __restrict__ w2,
                       const float* __restrict__ relTab,
                       unsigned short* __restrict__ qkvT, unsigned short* __restrict__ projT,
                       unsigned short* __restrict__ w1T, unsigned short* __restrict__ w2T,
                       float* __restrict__ biasT) {
    int idx = blockIdx.x * blockDim.x + threadIdx.x;
    if (idx < 110592) { int n = idx / 192, k = idx % 192; qkvT[idx] = f2bf(qkv_w[k * 576 + n]); return; }
    idx -= 110592;
    if (idx < 36864)  { int n = idx / 192, k = idx % 192; projT[idx] = f2bf(proj_w[k * 192 + n]); return; }
    idx -= 36864;
    if (idx < 73728)  { int n = idx / 192, k = idx % 192; w1T[idx] = f2bf(w1[k * 384 + n]); return; }
    idx -= 73728;
    if (idx < 73728)  { int n = idx / 384, k = idx % 384; w2T[idx] = f2bf(w2[k * 192 + n]); return; }
    idx -= 73728;
    if (idx < 24576) {
        int h = idx >> 12, i = (idx >> 6) & 63, j = idx & 63;
        int yi = i >> 3, xi = i & 7, yj = j >> 3, xj = j & 7;
        int rel = (yi - yj + 7) * 15 + (xi - xj + 7);
        biasT[idx] = relTab[rel * 6 + h];
    }
}

// FUSED Swin block: one window per block (2048 blocks), 8 waves (512 threads), 48 KB LDS.
// Disjoint-at-every-instant layout (two 24 KB regions):
//   R0 [0,24576):     A (swz [64][192]) -> VT full [6 head][32 d][64 tok] -> AO/A2 (swz [64][192])
//   R1 [24576,49152): Q [6][64][32] -> (qf loaded) -> K overwrite -> (kf loaded) ->
//                     P-half slots [6][64][32] -> G-half [64][192] in MLP
// Attention: 1 full head per wave (waves 0-5); P half0 via LDS, half1 packed in regs.
// MLP: two hidden halves through the 24 KB G buffer, accM accumulated.
__global__ __launch_bounds__(512, 4) void k_fused(
    const float* __restrict__ x,
    const float* __restrict__ n1g, const float* __restrict__ n1b,
    const unsigned short* __restrict__ qkvT, const float* __restrict__ qkv_b,
    const unsigned short* __restrict__ projT, const float* __restrict__ proj_b,
    const float* __restrict__ biasTab,
    const float* __restrict__ n2g, const float* __restrict__ n2b,
    const unsigned short* __restrict__ w1T, const float* __restrict__ b1,
    const unsigned short* __restrict__ w2T, const float* __restrict__ b2,
    float* __restrict__ out)
{
    __shared__ __align__(16) char smem[49152];
    __shared__ int sOpos[64];

    const int tid = threadIdx.x;
    const int wid = blockIdx.x;
    const int b = wid >> 6;
    const int win = wid & 63;
    const int wh = win >> 3, ww = win & 7;
    const int lane = tid & 63;
    const int w = tid >> 6;
    const int lhi = lane >> 4, llo = lane & 15;
    const int rg = w >> 2, cg = w & 3;   // row-group (2) x col-group (4)

    // ---------- Phase 1: LN1 + shifted window gather (8 threads/token) ----------
    {
        const int tok = tid >> 3;
        const int ch0 = (tid & 7) * 24;
        const int yi = tok >> 3, xi = tok & 7;
        const int oy = (wh * 8 + yi + 4) & 63;
        const int ox = (ww * 8 + xi + 4) & 63;
        const int base = ((b * 64 + oy) * 64 + ox) * CC;
        if ((tid & 7) == 0) sOpos[tok] = base;
        float v[24];
        float s = 0.f, ss = 0.f;
        #pragma unroll
        for (int i = 0; i < 6; ++i) {
            const float4 f = *(const float4*)(x + base + ch0 + i * 4);
            v[i*4+0]=f.x; v[i*4+1]=f.y; v[i*4+2]=f.z; v[i*4+3]=f.w;
            s  += f.x + f.y + f.z + f.w;
            ss += f.x*f.x + f.y*f.y + f.z*f.z + f.w*f.w;
        }
        s  += __shfl_xor(s, 1);  s  += __shfl_xor(s, 2);  s  += __shfl_xor(s, 4);
        ss += __shfl_xor(ss, 1); ss += __shfl_xor(ss, 2); ss += __shfl_xor(ss, 4);
        const float mean = s * (1.f / 192.f);
        const float rstd = rsqrtf(ss * (1.f / 192.f) - mean * mean + 1e-5f);
        char* aBase = smem + tok * 384;
        const int sw = (tok & 7) << 4;
        #pragma unroll
        for (int i = 0; i < 12; ++i) {
            const int c = ch0 + i * 2;
            const float a0 = (v[i*2+0] - mean) * rstd * n1g[c]   + n1b[c];
            const float a1 = (v[i*2+1] - mean) * rstd * n1g[c+1] + n1b[c+1];
            *(unsigned int*)(aBase + ((c * 2) ^ sw)) =
                (unsigned int)f2bf(a0) | ((unsigned int)f2bf(a1) << 16);
        }
    }
    __syncthreads();   // bar1: A ready

    // ---------- Phase 2: QKV GEMM: wave -> rows [32rg,+32) x cols [144cg,+144) ----------
    {
        f32x4 acc[2][9] = {};
        #pragma unroll
        for (int ks = 0; ks < 6; ++ks) {
            bf16x8 af[2];
            const int kbyte = ks * 64 + lhi * 16;
            #pragma unroll
            for (int m = 0; m < 2; ++m) {
                const int row = rg * 32 + m * 16 + llo;
                af[m] = *(const bf16x8*)(smem + row * 384 + (kbyte ^ ((row & 7) << 4)));
            }
            #pragma unroll
            for (int n = 0; n < 9; ++n) {
                const int col = cg * 144 + n * 16 + llo;
                const bf16x8 bfr = *(const bf16x8*)(qkvT + col * 192 + ks * 32 + lhi * 8);
                #pragma unroll
                for (int m = 0; m < 2; ++m) acc[m][n] = mfma16(af[m], bfr, acc[m][n]);
            }
        }
        __syncthreads();   // bar2: A dead everywhere

        // ---- 3a: scatter Q (xSCALE, +bias) -> R1 and VT -> R0 (K parts kept in regs) ----
        #pragma unroll
        for (int n = 0; n < 9; ++n) {
            const int c0 = cg * 144 + n * 16;
            const int which = c0 / 192;
            if (which != 1) {
                const int rem = c0 - which * 192;
                const int hh = rem >> 5;
                const int d = (rem & 31) + llo;
                const float bia = qkv_b[c0 + llo];
                #pragma unroll
                for (int m = 0; m < 2; ++m) {
                    #pragma unroll
                    for (int r = 0; r < 4; ++r) {
                        const int row = rg * 32 + m * 16 + lhi * 4 + r;
                        const float vv = acc[m][n][r] + bia;
                        if (which == 0)
                            *(unsigned short*)(smem + 24576 + hh * 4096 + row * 64 + ((2 * d) ^ ((row & 3) << 4)))
                                = f2bf(vv * 0.17677669529663687f);
                        else
                            *(unsigned short*)(smem + hh * 4096 + d * 128 + ((2 * row) ^ ((d & 7) << 4)))
                                = f2bf(vv);
                    }
                }
            }
        }
        __syncthreads();   // bar3: Q + VT visible

        // all attention waves load Q fragments
        bf16x8 qf[4];
        if (w < 6) {
            #pragma unroll
            for (int m = 0; m < 4; ++m) {
                const int t = m * 16 + llo;
                qf[m] = *(const bf16x8*)(smem + 24576 + w * 4096 + t * 64 + ((lhi * 16) ^ ((t & 3) << 4)));
            }
        }
        __syncthreads();   // bar4: qf in regs everywhere (lgkm drained) -> R1 reusable

        // ---- 3c: scatter K -> R1 (overwrites Q) ----
        #pragma unroll
        for (int n = 0; n < 9; ++n) {
            const int c0 = cg * 144 + n * 16;
            const int which = c0 / 192;
            if (which == 1) {
                const int rem = c0 - 192;
                const int hh = rem >> 5;
                const int d = (rem & 31) + llo;
                const float bia = qkv_b[c0 + llo];
                #pragma unroll
                for (int m = 0; m < 2; ++m) {
                    #pragma unroll
                    for (int r = 0; r < 4; ++r) {
                        const int row = rg * 32 + m * 16 + lhi * 4 + r;
                        *(unsigned short*)(smem + 24576 + hh * 4096 + row * 64 + ((2 * d) ^ ((row & 3) << 4)))
                            = f2bf(acc[m][n][r] + bia);
                    }
                }
            }
        }
        __syncthreads();   // bar5: K visible; acc dead

        // ---------- attention: one full head per wave (waves 0-5) ----------
        bf16x8 kf[4];
        if (w < 6) {
            #pragma unroll
            for (int n = 0; n < 4; ++n) {
                const int t = n * 16 + llo;
                kf[n] = *(const bf16x8*)(smem + 24576 + w * 4096 + t * 64 + ((lhi * 16) ^ ((t & 3) << 4)));
            }
        }
        __syncthreads();   // bar6: kf in regs -> R1 free for P-half slots

        f32x4 pacc[4][2] = {};
        float rinv[4][4];
        if (w < 6) {
            f32x4 sacc[4][4] = {};
            #pragma unroll
            for (int m = 0; m < 4; ++m)
                #pragma unroll
                for (int n = 0; n < 4; ++n)
                    sacc[m][n] = mfma16(qf[m], kf[n], sacc[m][n]);

            const bool eH = (wh == 7), eW = (ww == 7);
            int idj[4];
            #pragma unroll
            for (int n = 0; n < 4; ++n) {
                const int j = n * 16 + llo;
                idj[n] = (eH ? ((j >> 3) >= 4 ? 2 : 1) : 0) * 3 + (eW ? ((j & 7) >= 4 ? 2 : 1) : 0);
            }
            const float* bT = biasTab + w * 4096;
            char* const pslot = smem + 24576 + w * 4096;
            unsigned pb1[4][4];
            // no-max softmax (scores O(1), f32-exp exact); half0 -> LDS, half1 packed
            #pragma unroll
            for (int m = 0; m < 4; ++m) {
                #pragma unroll
                for (int r = 0; r < 4; ++r) {
                    const int i = m * 16 + lhi * 4 + r;
                    const int idi = (eH ? ((i >> 3) >= 4 ? 2 : 1) : 0) * 3 +
                                    (eW ? ((i & 7) >= 4 ? 2 : 1) : 0);
                    float sum = 0.f;
                    unsigned short pb[4];
                    #pragma unroll
                    for (int n = 0; n < 4; ++n) {
                        const int j = n * 16 + llo;
                        float e = __expf(sacc[m][n][r] + bT[i * 64 + j]);
                        if (idi != idj[n]) e = 0.f;
                        sum += e;
                        pb[n] = f2bf(e);
                    }
                    sum += __shfl_xor(sum, 1);
                    sum += __shfl_xor(sum, 2);
                    sum += __shfl_xor(sum, 4);
                    sum += __shfl_xor(sum, 8);
                    rinv[m][r] = 1.f / sum;
                    const int sw = (i & 3) << 4;
                    *(unsigned short*)(pslot + i * 64 + ((2 * llo) ^ sw)) = pb[0];
                    *(unsigned short*)(pslot + i * 64 + ((2 * (16 + llo)) ^ sw)) = pb[1];
                    pb1[m][r] = (unsigned)pb[2] | ((unsigned)pb[3] << 16);
                }
            }
            // PV pass0: P[:,0:32] x V[0:32,:]  (wave-private slot; VT stable since bar3)
            {
                bf16x8 pf[4];
                #pragma unroll
                for (int m = 0; m < 4; ++m) {
                    const int t = m * 16 + llo;
                    pf[m] = *(const bf16x8*)(pslot + t * 64 + ((lhi * 16) ^ ((t & 3) << 4)));
                }
                #pragma unroll
                for (int n = 0; n < 2; ++n) {
                    const int d = n * 16 + llo;
                    const bf16x8 vf = *(const bf16x8*)(smem + w * 4096 + d * 128 + ((lhi * 16) ^ ((d & 7) << 4)));
                    #pragma unroll
                    for (int m = 0; m < 4; ++m) pacc[m][n] = mfma16(pf[m], vf, pacc[m][n]);
                }
            }
            // write P half1 into the same slot (same-wave ordering), PV pass1
            #pragma unroll
            for (int m = 0; m < 4; ++m) {
                #pragma unroll
                for (int r = 0; r < 4; ++r) {
                    const int i = m * 16 + lhi * 4 + r;
                    const int sw = (i & 3) << 4;
                    const unsigned u = pb1[m][r];
                    *(unsigned short*)(pslot + i * 64 + ((2 * llo) ^ sw)) = (unsigned short)u;
                    *(unsigned short*)(pslot + i * 64 + ((2 * (16 + llo)) ^ sw)) = (unsigned short)(u >> 16);
                }
            }
            {
                bf16x8 pf[4];
                #pragma unroll
                for (int m = 0; m < 4; ++m) {
                    const int t = m * 16 + llo;
                    pf[m] = *(const bf16x8*)(pslot + t * 64 + ((lhi * 16) ^ ((t & 3) << 4)));
                }
                #pragma unroll
                for (int n = 0; n < 2; ++n) {
                    const int d = n * 16 + llo;
                    const bf16x8 vf = *(const bf16x8*)(smem + w * 4096 + d * 128 + ((64 + lhi * 16) ^ ((d & 7) << 4)));
                    #pragma unroll
                    for (int m = 0; m < 4; ++m) pacc[m][n] = mfma16(pf[m], vf, pacc[m][n]);
                }
            }
        }
        __syncthreads();   // bar7: PV done; VT dead -> R0 free for AO

        if (w < 6) {
            #pragma unroll
            for (int m = 0; m < 4; ++m) {
                #pragma unroll
                for (int n = 0; n < 2; ++n) {
                    const int c = w * 32 + n * 16 + llo;
                    #pragma unroll
                    for (int r = 0; r < 4; ++r) {
                        const int i = m * 16 + lhi * 4 + r;
                        *(unsigned short*)(smem + i * 384 + ((c * 2) ^ ((i & 7) << 4)))
                            = f2bf(pacc[m][n][r] * rinv[m][r]);
                    }
                }
            }
        }
    }
    __syncthreads();   // bar8: AO ready

    // ---------- Phase 4: proj GEMM + residual: rows [32rg,+32) x cols [48cg,+48) ----------
    {
        f32x4 acc[2][3] = {};
        #pragma unroll
        for (int ks = 0; ks < 6; ++ks) {
            bf16x8 af[2];
            const int kbyte = ks * 64 + lhi * 16;
            #pragma unroll
            for (int m = 0; m < 2; ++m) {
                const int row = rg * 32 + m * 16 + llo;
                af[m] = *(const bf16x8*)(smem + row * 384 + (kbyte ^ ((row & 7) << 4)));
            }
            #pragma unroll
            for (int n = 0; n < 3; ++n) {
                const int col = cg * 48 + n * 16 + llo;
                const bf16x8 bfr = *(const bf16x8*)(projT + col * 192 + ks * 32 + lhi * 8);
                #pragma unroll
                for (int m = 0; m < 2; ++m) acc[m][n] = mfma16(af[m], bfr, acc[m][n]);
            }
        }
        #pragma unroll
        for (int n = 0; n < 3; ++n) {
            const int c = cg * 48 + n * 16 + llo;
            const float pb = proj_b[c];
            #pragma unroll
            for (int m = 0; m < 2; ++m) {
                #pragma unroll
                for (int r = 0; r < 4; ++r) {
                    const int i = rg * 32 + m * 16 + lhi * 4 + r;
                    const int base = sOpos[i];
                    out[base + c] = x[base + c] + acc[m][n][r] + pb;
                }
            }
        }
    }
    __syncthreads();   // bar9: h fully written (vmcnt drained at barrier)

    // ---------- Phase 5: LN2 from out (L1/L2-hot) -> A2 at R0 ----------
    {
        const int tok = tid >> 3;
        const int ch0 = (tid & 7) * 24;
        const float* hp = out + sOpos[tok];
        float v[24]; float s = 0.f, ss = 0.f;
        #pragma unroll
        for (int i = 0; i < 6; ++i) {
            const float4 f = *(const float4*)(hp + ch0 + i * 4);
            v[i*4]=f.x; v[i*4+1]=f.y; v[i*4+2]=f.z; v[i*4+3]=f.w;
            s += f.x + f.y + f.z + f.w;
            ss += f.x*f.x + f.y*f.y + f.z*f.z + f.w*f.w;
        }
        s  += __shfl_xor(s, 1);  s  += __shfl_xor(s, 2);  s  += __shfl_xor(s, 4);
        ss += __shfl_xor(ss, 1); ss += __shfl_xor(ss, 2); ss += __shfl_xor(ss, 4);
        const float mean = s * (1.f / 192.f);
        const float rstd = rsqrtf(ss * (1.f / 192.f) - mean * mean + 1e-5f);
        char* aBase = smem + tok * 384;
        const int sw = (tok & 7) << 4;
        #pragma unroll
        for (int i = 0; i < 12; ++i) {
            const int c = ch0 + i * 2;
            const float a0 = (v[i*2]   - mean) * rstd * n2g[c]   + n2b[c];
            const float a1 = (v[i*2+1] - mean) * rstd * n2g[c+1] + n2b[c+1];
            *(unsigned int*)(aBase + ((c * 2) ^ sw)) =
                (unsigned int)f2bf(a0) | ((unsigned int)f2bf(a1) << 16);
        }
    }
    __syncthreads();   // bar10: A2 ready; R1 free for G-half

    // ---------- Phase 6: MLP in two hidden halves; G-half [64][192] at R1 ----------
    f32x4 accM[2][3] = {};
    #pragma unroll
    for (int hh = 0; hh < 2; ++hh) {
        // GEMM1 half: rows [32rg,+32) x cols [hh*192 + 48cg, +48), + exact GELU -> G-half
        {
            f32x4 a1[2][3] = {};
            #pragma unroll
            for (int ks = 0; ks < 6; ++ks) {
                bf16x8 af[2];
                const int kbyte = ks * 64 + lhi * 16;
                #pragma unroll
                for (int m = 0; m < 2; ++m) {
                    const int row = rg * 32 + m * 16 + llo;
                    af[m] = *(const bf16x8*)(smem + row * 384 + (kbyte ^ ((row & 7) << 4)));
                }
                #pragma unroll
                for (int n = 0; n < 3; ++n) {
                    const int col = hh * 192 + cg * 48 + n * 16 + llo;
                    const bf16x8 bfr = *(const bf16x8*)(w1T + col * 192 + ks * 32 + lhi * 8);
                    #pragma unroll
                    for (int m = 0; m < 2; ++m) a1[m][n] = mfma16(af[m], bfr, a1[m][n]);
                }
            }
            #pragma unroll
            for (int n = 0; n < 3; ++n) {
                const int cl = cg * 48 + n * 16 + llo;
                const float bb = b1[hh * 192 + cl];
                #pragma unroll
                for (int m = 0; m < 2; ++m) {
                    #pragma unroll
                    for (int r = 0; r < 4; ++r) {
                        const int i = rg * 32 + m * 16 + lhi * 4 + r;
                        const float u = a1[m][n][r] + bb;
                        const float g = 0.5f * u * (1.f + erff(u * 0.70710678118654752f));
                        *(unsigned short*)(smem + 24576 + i * 384 + ((2 * cl) ^ ((i & 7) << 4))) = f2bf(g);
                    }
                }
            }
        }
        __syncthreads();   // G-half ready
        // GEMM2 partial: K = [hh*192,+192): rows [32rg,+32) x cols [48cg,+48)
        {
            #pragma unroll
            for (int ks = 0; ks < 6; ++ks) {
                bf16x8 af[2];
                const int kbyte = ks * 64 + lhi * 16;
                #pragma unroll
                for (int m = 0; m < 2; ++m) {
                    const int row = rg * 32 + m * 16 + llo;
                    af[m] = *(const bf16x8*)(smem + 24576 + row * 384 + (kbyte ^ ((row & 7) << 4)));
                }
                #pragma unroll
                for (int n = 0; n < 3; ++n) {
                    const int col = cg * 48 + n * 16 + llo;
                    const bf16x8 bfr = *(const bf16x8*)(w2T + col * 384 + hh * 192 + ks * 32 + lhi * 8);
                    #pragma unroll
                    for (int m = 0; m < 2; ++m) accM[m][n] = mfma16(af[m], bfr, accM[m][n]);
                }
            }
        }
        __syncthreads();   // G-half consumed (safe to overwrite)
    }
    // final residual writeout
    {
        #pragma unroll
        for (int n = 0; n < 3; ++n) {
            const int c = cg * 48 + n * 16 + llo;
            const float bb = b2[c];
            #pragma unroll
            for (int m = 0; m < 2; ++m) {
                #pragma unroll
                for (int r = 0; r < 4; ++r) {
                    const int i = rg * 32 + m * 16 + lhi * 4 + r;
                    float* p = out + sOpos[i] + c;
                    *p = *p + accM[m][n][r] + bb;
                }
            }
        }
    }
}

extern "C" void kernel_launch(void* const* d_in, const int* in_sizes, int n_in,
                              void* d_out, int out_size, void* d_ws, size_t ws_size,
                              hipStream_t stream)
{
    const float* x      = (const float*)d_in[0];
    const float* n1g    = (const float*)d_in[1];
    const float* n1b    = (const float*)d_in[2];
    const float* qkv_w  = (const float*)d_in[3];
    const float* qkv_b  = (const float*)d_in[4];
    const float* proj_w = (const float*)d_in[5];
    const float* proj_b = (const float*)d_in[6];
    const float* relTab = (const float*)d_in[7];
    const float* n2g    = (const float*)d_in[8];
    const float* n2b    = (const float*)d_in[9];
    const float* w1     = (const float*)d_in[10];
    const float* b1     = (const float*)d_in[11];
    const float* w2     = (const float*)d_in[12];
    const float* b2     = (const float*)d_in[13];
    float* out = (float*)d_out;

    char* ws = (char*)d_ws;
    unsigned short* qkvT  = (unsigned short*)(ws);            // [576][192] bf16
    unsigned short* projT = (unsigned short*)(ws + 221184);   // [192][192] bf16
    unsigned short* w1T   = (unsigned short*)(ws + 294912);   // [384][192] bf16
    unsigned short* w2T   = (unsigned short*)(ws + 442368);   // [192][384] bf16
    float*          biasT = (float*)(ws + 589824);            // [6][64][64] f32

    k_prep<<<1248, 256, 0, stream>>>(qkv_w, proj_w, w1, w2, relTab, qkvT, projT, w1T, w2T, biasT);
    k_fused<<<2048, 512, 0, stream>>>(x, n1g, n1b, qkvT, qkv_b, projT, proj_b, biasT,
                                      n2g, n2b, w1T, b1, w2T, b2, out);
}

// Round 13
// 379.845 us; speedup vs baseline: 1.1582x; 1.1582x over previous
//
#include <hip/hip_runtime.h>
#include <hip/hip_bf16.h>

#define CC 192

typedef __attribute__((ext_vector_type(8))) short bf16x8;
typedef __attribute__((ext_vector_type(4))) float f32x4;

__device__ __forceinline__ unsigned short f2bf(float f) {
    unsigned int u = __float_as_uint(f);
    u = (u + 0x7fffu + ((u >> 16) & 1u)) >> 16;
    return (unsigned short)u;
}

__device__ __forceinline__ f32x4 mfma16(bf16x8 a, bf16x8 b, f32x4 c) {
    return __builtin_amdgcn_mfma_f32_16x16x32_bf16(a, b, c, 0, 0, 0);
}

// Merged prep: 4 weight transposes (f32 [K][N] -> bf16 [N][K]) + bias expand.
__global__ void k_prep(const float* __restrict__ qkv_w, const float* __restrict__ proj_w,
                       const float* __restrict__ w1, const float* __restrict__ w2,
                       const float* __restrict__ relTab,
                       unsigned short* __restrict__ qkvT, unsigned short* __restrict__ projT,
                       unsigned short* __restrict__ w1T, unsigned short* __restrict__ w2T,
                       float* __restrict__ biasT) {
    int idx = blockIdx.x * blockDim.x + threadIdx.x;
    if (idx < 110592) { int n = idx / 192, k = idx % 192; qkvT[idx] = f2bf(qkv_w[k * 576 + n]); return; }
    idx -= 110592;
    if (idx < 36864)  { int n = idx / 192, k = idx % 192; projT[idx] = f2bf(proj_w[k * 192 + n]); return; }
    idx -= 36864;
    if (idx < 73728)  { int n = idx / 192, k = idx % 192; w1T[idx] = f2bf(w1[k * 384 + n]); return; }
    idx -= 73728;
    if (idx < 73728)  { int n = idx / 384, k = idx % 384; w2T[idx] = f2bf(w2[k * 192 + n]); return; }
    idx -= 73728;
    if (idx < 24576) {
        int h = idx >> 12, i = (idx >> 6) & 63, j = idx & 63;
        int yi = i >> 3, xi = i & 7, yj = j >> 3, xj = j & 7;
        int rel = (yi - yj + 7) * 15 + (xi - xj + 7);
        biasT[idx] = relTab[rel * 6 + h];
    }
}

// FUSED Swin block: one window/block (2048 blocks), 8 waves (512 threads), 60 KB LDS.
// Design rule learned R5/R8/R10/R12: EVERY program point's static live set must fit the
// per-wave register budget (128 at 4 waves/SIMD). Attention therefore runs in two
// sequential row-halves (sacc[2][4] at a time); VT is staged FULL in LDS (nothing held
// in regs across attention); K is the halved buffer (dies into kf regs immediately).
// LDS map (smem[61440]):
//   QS  [0,24576):      A -> Q slots [6][64][32] -> P-half (own slot) -> AO -> A2
//   VS  [24576,49152):  VT full [6][32 d][64 tok] -> G-half [64][192] (MLP)
//   KH  [49152,61440):  K halves [6][32 tok][32 d] (half0, then half1 overwrites)
__global__ __launch_bounds__(512, 4) void k_fused(
    const float* __restrict__ x,
    const float* __restrict__ n1g, const float* __restrict__ n1b,
    const unsigned short* __restrict__ qkvT, const float* __restrict__ qkv_b,
    const unsigned short* __restrict__ projT, const float* __restrict__ proj_b,
    const float* __restrict__ biasTab,
    const float* __restrict__ n2g, const float* __restrict__ n2b,
    const unsigned short* __restrict__ w1T, const float* __restrict__ b1,
    const unsigned short* __restrict__ w2T, const float* __restrict__ b2,
    float* __restrict__ out)
{
    __shared__ __align__(16) char smem[61440];
    __shared__ int sOpos[64];

    const int tid = threadIdx.x;
    const int wid = blockIdx.x;
    const int b = wid >> 6;
    const int win = wid & 63;
    const int wh = win >> 3, ww = win & 7;
    const int lane = tid & 63;
    const int w = tid >> 6;
    const int lhi = lane >> 4, llo = lane & 15;
    const int rg = w >> 2, cg = w & 3;

    // ---------- Phase 1: LN1 + shifted window gather (8 threads/token) ----------
    {
        const int tok = tid >> 3;
        const int ch0 = (tid & 7) * 24;
        const int yi = tok >> 3, xi = tok & 7;
        const int oy = (wh * 8 + yi + 4) & 63;
        const int ox = (ww * 8 + xi + 4) & 63;
        const int base = ((b * 64 + oy) * 64 + ox) * CC;
        if ((tid & 7) == 0) sOpos[tok] = base;
        float v[24];
        float s = 0.f, ss = 0.f;
        #pragma unroll
        for (int i = 0; i < 6; ++i) {
            const float4 f = *(const float4*)(x + base + ch0 + i * 4);
            v[i*4+0]=f.x; v[i*4+1]=f.y; v[i*4+2]=f.z; v[i*4+3]=f.w;
            s  += f.x + f.y + f.z + f.w;
            ss += f.x*f.x + f.y*f.y + f.z*f.z + f.w*f.w;
        }
        s  += __shfl_xor(s, 1);  s  += __shfl_xor(s, 2);  s  += __shfl_xor(s, 4);
        ss += __shfl_xor(ss, 1); ss += __shfl_xor(ss, 2); ss += __shfl_xor(ss, 4);
        const float mean = s * (1.f / 192.f);
        const float rstd = rsqrtf(ss * (1.f / 192.f) - mean * mean + 1e-5f);
        char* aBase = smem + tok * 384;
        const int sw = (tok & 7) << 4;
        #pragma unroll
        for (int i = 0; i < 12; ++i) {
            const int c = ch0 + i * 2;
            const float a0 = (v[i*2+0] - mean) * rstd * n1g[c]   + n1b[c];
            const float a1 = (v[i*2+1] - mean) * rstd * n1g[c+1] + n1b[c+1];
            *(unsigned int*)(aBase + ((c * 2) ^ sw)) =
                (unsigned int)f2bf(a0) | ((unsigned int)f2bf(a1) << 16);
        }
    }
    __syncthreads();   // bar1: A ready

    // ---------- Phase 2a: QK GEMM — waves 0-3: Q cols [48w,+48); 4-7: K cols [192+48(w-4),+48) ----------
    f32x4 aQK[4][3] = {};
    const int qkc = (w < 4) ? (48 * w) : (192 + 48 * (w - 4));
    {
        #pragma unroll
        for (int ks = 0; ks < 6; ++ks) {
            bf16x8 af[4];
            const int kbyte = ks * 64 + lhi * 16;
            #pragma unroll
            for (int m = 0; m < 4; ++m) {
                const int row = m * 16 + llo;
                af[m] = *(const bf16x8*)(smem + row * 384 + (kbyte ^ ((row & 7) << 4)));
            }
            #pragma unroll
            for (int n = 0; n < 3; ++n) {
                const bf16x8 bfr = *(const bf16x8*)(qkvT + (qkc + n * 16 + llo) * 192 + ks * 32 + lhi * 8);
                #pragma unroll
                for (int m = 0; m < 4; ++m) aQK[m][n] = mfma16(af[m], bfr, aQK[m][n]);
            }
        }
    }
    // ---------- Phase 2b: V GEMM — rows [32rg,+32) x V-cols [48cg,+48) ----------
    f32x4 aV[2][3] = {};
    const int vc = 48 * cg;
    {
        #pragma unroll
        for (int ks = 0; ks < 6; ++ks) {
            bf16x8 af[2];
            const int kbyte = ks * 64 + lhi * 16;
            #pragma unroll
            for (int m = 0; m < 2; ++m) {
                const int row = rg * 32 + m * 16 + llo;
                af[m] = *(const bf16x8*)(smem + row * 384 + (kbyte ^ ((row & 7) << 4)));
            }
            #pragma unroll
            for (int n = 0; n < 3; ++n) {
                const bf16x8 bfr = *(const bf16x8*)(qkvT + (384 + vc + n * 16 + llo) * 192 + ks * 32 + lhi * 8);
                #pragma unroll
                for (int m = 0; m < 2; ++m) aV[m][n] = mfma16(af[m], bfr, aV[m][n]);
            }
        }
    }
    __syncthreads();   // bar2: A dead everywhere

    // ---------- Phase 3: scatter Q (xSCALE) / K-half0 / VT-full ----------
    if (w < 4) {
        #pragma unroll
        for (int n = 0; n < 3; ++n) {
            const int c0 = qkc + n * 16;
            const int head = c0 >> 5;
            const int d = (c0 & 31) + llo;
            const float bia = qkv_b[c0 + llo];
            #pragma unroll
            for (int m = 0; m < 4; ++m) {
                #pragma unroll
                for (int r = 0; r < 4; ++r) {
                    const int row = m * 16 + lhi * 4 + r;
                    *(unsigned short*)(smem + head * 4096 + row * 64 + ((2 * d) ^ ((row & 3) << 4)))
                        = f2bf((aQK[m][n][r] + bia) * 0.17677669529663687f);
                }
            }
        }
    } else {
        #pragma unroll
        for (int n = 0; n < 3; ++n) {
            const int c0 = qkc + n * 16;
            const int rem = c0 - 192;
            const int head = rem >> 5;
            const int d = (rem & 31) + llo;
            const float bia = qkv_b[c0 + llo];
            #pragma unroll
            for (int m = 0; m < 2; ++m) {   // K half0: rows 0..31; m=2,3 held in regs
                #pragma unroll
                for (int r = 0; r < 4; ++r) {
                    const int row = m * 16 + lhi * 4 + r;
                    *(unsigned short*)(smem + 49152 + head * 2048 + row * 64 + ((2 * d) ^ ((row & 3) << 4)))
                        = f2bf(aQK[m][n][r] + bia);
                }
            }
        }
    }
    {
        #pragma unroll
        for (int n = 0; n < 3; ++n) {
            const int cv = vc + n * 16;
            const int head = cv >> 5;
            const int dl = (cv & 31) + llo;
            const float bia = qkv_b[384 + cv + llo];
            #pragma unroll
            for (int m = 0; m < 2; ++m) {
                #pragma unroll
                for (int r = 0; r < 4; ++r) {
                    const int tok = rg * 32 + m * 16 + lhi * 4 + r;
                    *(unsigned short*)(smem + 24576 + head * 4096 + dl * 128 + ((2 * tok) ^ ((dl & 7) << 4)))
                        = f2bf(aV[m][n][r] + bia);
                }
            }
        }
    }
    __syncthreads();   // bar3: Q / K-half0 / VT visible

    // ---------- Phase 4: attention (waves 0-5, one head each, two sequential row-halves) ----------
    bf16x8 qf[4], kf[4];
    if (w < 6) {
        #pragma unroll
        for (int m = 0; m < 4; ++m) {
            const int t = m * 16 + llo;
            qf[m] = *(const bf16x8*)(smem + w * 4096 + t * 64 + ((lhi * 16) ^ ((t & 3) << 4)));
        }
        #pragma unroll
        for (int n = 0; n < 2; ++n) {
            const int t = n * 16 + llo;
            kf[n] = *(const bf16x8*)(smem + 49152 + w * 2048 + t * 64 + ((lhi * 16) ^ ((t & 3) << 4)));
        }
    }
    __syncthreads();   // bar4: half0 kf loaded everywhere -> KH writable

    if (w >= 4) {   // K half1 scatter (rows 32..63, from held regs)
        #pragma unroll
        for (int n = 0; n < 3; ++n) {
            const int c0 = qkc + n * 16;
            const int rem = c0 - 192;
            const int head = rem >> 5;
            const int d = (rem & 31) + llo;
            const float bia = qkv_b[c0 + llo];
            #pragma unroll
            for (int m = 2; m < 4; ++m) {
                #pragma unroll
                for (int r = 0; r < 4; ++r) {
                    const int rl = m * 16 + lhi * 4 + r - 32;
                    *(unsigned short*)(smem + 49152 + head * 2048 + rl * 64 + ((2 * d) ^ ((rl & 3) << 4)))
                        = f2bf(aQK[m][n][r] + bia);
                }
            }
        }
    }
    __syncthreads();   // bar5: K half1 ready

    f32x4 pacc[2][2][2] = {};
    float rinv[2][2][4];
    if (w < 6) {
        #pragma unroll
        for (int n = 2; n < 4; ++n) {
            const int tl = (n - 2) * 16 + llo;
            kf[n] = *(const bf16x8*)(smem + 49152 + w * 2048 + tl * 64 + ((lhi * 16) ^ ((tl & 3) << 4)));
        }
        const bool eH = (wh == 7), eW = (ww == 7);
        int idj[4];
        #pragma unroll
        for (int n = 0; n < 4; ++n) {
            const int j = n * 16 + llo;
            idj[n] = (eH ? ((j >> 3) >= 4 ? 2 : 1) : 0) * 3 + (eW ? ((j & 7) >= 4 ? 2 : 1) : 0);
        }
        const float* bT = biasTab + w * 4096;
        char* const pslot = smem + w * 4096;

        #pragma unroll
        for (int hh = 0; hh < 2; ++hh) {
            f32x4 sacc[2][4] = {};
            #pragma unroll
            for (int m = 0; m < 2; ++m)
                #pragma unroll
                for (int n = 0; n < 4; ++n)
                    sacc[m][n] = mfma16(qf[hh * 2 + m], kf[n], sacc[m][n]);

            // no-max softmax (scores O(1), f32-exp exact); P-half -> own (dead-Q) slot
            #pragma unroll
            for (int m = 0; m < 2; ++m) {
                #pragma unroll
                for (int r = 0; r < 4; ++r) {
                    const int il = m * 16 + lhi * 4 + r;
                    const int i = hh * 32 + il;
                    const int idi = (eH ? ((i >> 3) >= 4 ? 2 : 1) : 0) * 3 +
                                    (eW ? ((i & 7) >= 4 ? 2 : 1) : 0);
                    float sum = 0.f;
                    unsigned short pb[4];
                    #pragma unroll
                    for (int n = 0; n < 4; ++n) {
                        const int j = n * 16 + llo;
                        float e = __expf(sacc[m][n][r] + bT[i * 64 + j]);
                        if (idi != idj[n]) e = 0.f;
                        sum += e;
                        pb[n] = f2bf(e);
                    }
                    sum += __shfl_xor(sum, 1);
                    sum += __shfl_xor(sum, 2);
                    sum += __shfl_xor(sum, 4);
                    sum += __shfl_xor(sum, 8);
                    rinv[hh][m][r] = 1.f / sum;
                    #pragma unroll
                    for (int n = 0; n < 4; ++n) {
                        const int j = n * 16 + llo;
                        *(unsigned short*)(pslot + il * 128 + ((2 * j) ^ ((il & 7) << 4))) = pb[n];
                    }
                }
            }
            // PV for this half: P(32x64) x VT(full) -> pacc[hh]
            #pragma unroll
            for (int ks = 0; ks < 2; ++ks) {
                bf16x8 pf[2];
                #pragma unroll
                for (int m = 0; m < 2; ++m) {
                    const int t = m * 16 + llo;
                    pf[m] = *(const bf16x8*)(pslot + t * 128 + ((ks * 64 + lhi * 16) ^ ((t & 7) << 4)));
                }
                #pragma unroll
                for (int n = 0; n < 2; ++n) {
                    const int d = n * 16 + llo;
                    const bf16x8 vf = *(const bf16x8*)(smem + 24576 + w * 4096 + d * 128 + ((ks * 64 + lhi * 16) ^ ((d & 7) << 4)));
                    #pragma unroll
                    for (int m = 0; m < 2; ++m) pacc[hh][m][n] = mfma16(pf[m], vf, pacc[hh][m][n]);
                }
            }
        }
    }
    __syncthreads();   // bar6: PV done everywhere; QS (P) and VS (VT) dead

    if (w < 6) {   // AO -> [0,24576) swz [64][192]
        #pragma unroll
        for (int hh = 0; hh < 2; ++hh) {
            #pragma unroll
            for (int m = 0; m < 2; ++m) {
                #pragma unroll
                for (int n = 0; n < 2; ++n) {
                    const int c = w * 32 + n * 16 + llo;
                    #pragma unroll
                    for (int r = 0; r < 4; ++r) {
                        const int i = hh * 32 + m * 16 + lhi * 4 + r;
                        *(unsigned short*)(smem + i * 384 + ((c * 2) ^ ((i & 7) << 4)))
                            = f2bf(pacc[hh][m][n][r] * rinv[hh][m][r]);
                    }
                }
            }
        }
    }
    __syncthreads();   // bar7: AO ready

    // ---------- Phase 5: proj GEMM + residual: rows [32rg,+32) x cols [48cg,+48) ----------
    {
        f32x4 acc[2][3] = {};
        #pragma unroll
        for (int ks = 0; ks < 6; ++ks) {
            bf16x8 af[2];
            const int kbyte = ks * 64 + lhi * 16;
            #pragma unroll
            for (int m = 0; m < 2; ++m) {
                const int row = rg * 32 + m * 16 + llo;
                af[m] = *(const bf16x8*)(smem + row * 384 + (kbyte ^ ((row & 7) << 4)));
            }
            #pragma unroll
            for (int n = 0; n < 3; ++n) {
                const int col = cg * 48 + n * 16 + llo;
                const bf16x8 bfr = *(const bf16x8*)(projT + col * 192 + ks * 32 + lhi * 8);
                #pragma unroll
                for (int m = 0; m < 2; ++m) acc[m][n] = mfma16(af[m], bfr, acc[m][n]);
            }
        }
        #pragma unroll
        for (int n = 0; n < 3; ++n) {
            const int c = cg * 48 + n * 16 + llo;
            const float pb = proj_b[c];
            #pragma unroll
            for (int m = 0; m < 2; ++m) {
                #pragma unroll
                for (int r = 0; r < 4; ++r) {
                    const int i = rg * 32 + m * 16 + lhi * 4 + r;
                    const int base = sOpos[i];
                    out[base + c] = x[base + c] + acc[m][n][r] + pb;
                }
            }
        }
    }
    __syncthreads();   // bar8: h written (vmcnt drained); AO dead

    // ---------- Phase 6: LN2 from out (L1/L2-hot) -> A2 at [0,24576) ----------
    {
        const int tok = tid >> 3;
        const int ch0 = (tid & 7) * 24;
        const float* hp = out + sOpos[tok];
        float v[24]; float s = 0.f, ss = 0.f;
        #pragma unroll
        for (int i = 0; i < 6; ++i) {
            const float4 f = *(const float4*)(hp + ch0 + i * 4);
            v[i*4]=f.x; v[i*4+1]=f.y; v[i*4+2]=f.z; v[i*4+3]=f.w;
            s += f.x + f.y + f.z + f.w;
            ss += f.x*f.x + f.y*f.y + f.z*f.z + f.w*f.w;
        }
        s  += __shfl_xor(s, 1);  s  += __shfl_xor(s, 2);  s  += __shfl_xor(s, 4);
        ss += __shfl_xor(ss, 1); ss += __shfl_xor(ss, 2); ss += __shfl_xor(ss, 4);
        const float mean = s * (1.f / 192.f);
        const float rstd = rsqrtf(ss * (1.f / 192.f) - mean * mean + 1e-5f);
        char* aBase = smem + tok * 384;
        const int sw = (tok & 7) << 4;
        #pragma unroll
        for (int i = 0; i < 12; ++i) {
            const int c = ch0 + i * 2;
            const float a0 = (v[i*2]   - mean) * rstd * n2g[c]   + n2b[c];
            const float a1 = (v[i*2+1] - mean) * rstd * n2g[c+1] + n2b[c+1];
            *(unsigned int*)(aBase + ((c * 2) ^ sw)) =
                (unsigned int)f2bf(a0) | ((unsigned int)f2bf(a1) << 16);
        }
    }
    __syncthreads();   // bar9: A2 ready; VS region free for G-half

    // ---------- Phase 7: MLP in two hidden halves; G-half [64][192] at [24576,49152) ----------
    f32x4 accM[2][3] = {};
    #pragma unroll
    for (int hh = 0; hh < 2; ++hh) {
        {
            f32x4 a1[2][3] = {};
            #pragma unroll
            for (int ks = 0; ks < 6; ++ks) {
                bf16x8 af[2];
                const int kbyte = ks * 64 + lhi * 16;
                #pragma unroll
                for (int m = 0; m < 2; ++m) {
                    const int row = rg * 32 + m * 16 + llo;
                    af[m] = *(const bf16x8*)(smem + row * 384 + (kbyte ^ ((row & 7) << 4)));
                }
                #pragma unroll
                for (int n = 0; n < 3; ++n) {
                    const int col = hh * 192 + cg * 48 + n * 16 + llo;
                    const bf16x8 bfr = *(const bf16x8*)(w1T + col * 192 + ks * 32 + lhi * 8);
                    #pragma unroll
                    for (int m = 0; m < 2; ++m) a1[m][n] = mfma16(af[m], bfr, a1[m][n]);
                }
            }
            #pragma unroll
            for (int n = 0; n < 3; ++n) {
                const int cl = cg * 48 + n * 16 + llo;
                const float bb = b1[hh * 192 + cl];
                #pragma unroll
                for (int m = 0; m < 2; ++m) {
                    #pragma unroll
                    for (int r = 0; r < 4; ++r) {
                        const int i = rg * 32 + m * 16 + lhi * 4 + r;
                        const float u = a1[m][n][r] + bb;
                        const float g = 0.5f * u * (1.f + erff(u * 0.70710678118654752f));
                        *(unsigned short*)(smem + 24576 + i * 384 + ((2 * cl) ^ ((i & 7) << 4))) = f2bf(g);
                    }
                }
            }
        }
        __syncthreads();   // G-half ready
        {
            #pragma unroll
            for (int ks = 0; ks < 6; ++ks) {
                bf16x8 af[2];
                const int kbyte = ks * 64 + lhi * 16;
                #pragma unroll
                for (int m = 0; m < 2; ++m) {
                    const int row = rg * 32 + m * 16 + llo;
                    af[m] = *(const bf16x8*)(smem + 24576 + row * 384 + (kbyte ^ ((row & 7) << 4)));
                }
                #pragma unroll
                for (int n = 0; n < 3; ++n) {
                    const int col = cg * 48 + n * 16 + llo;
                    const bf16x8 bfr = *(const bf16x8*)(w2T + col * 384 + hh * 192 + ks * 32 + lhi * 8);
                    #pragma unroll
                    for (int m = 0; m < 2; ++m) accM[m][n] = mfma16(af[m], bfr, accM[m][n]);
                }
            }
        }
        __syncthreads();   // G-half consumed
    }
    {
        #pragma unroll
        for (int n = 0; n < 3; ++n) {
            const int c = cg * 48 + n * 16 + llo;
            const float bb = b2[c];
            #pragma unroll
            for (int m = 0; m < 2; ++m) {
                #pragma unroll
                for (int r = 0; r < 4; ++r) {
                    const int i = rg * 32 + m * 16 + lhi * 4 + r;
                    float* p = out + sOpos[i] + c;
                    *p = *p + accM[m][n][r] + bb;
                }
            }
        }
    }
}

extern "C" void kernel_launch(void* const* d_in, const int* in_sizes, int n_in,
                              void* d_out, int out_size, void* d_ws, size_t ws_size,
                              hipStream_t stream)
{
    const float* x      = (const float*)d_in[0];
    const float* n1g    = (const float*)d_in[1];
    const float* n1b    = (const float*)d_in[2];
    const float* qkv_w  = (const float*)d_in[3];
    const float* qkv_b  = (const float*)d_in[4];
    const float* proj_w = (const float*)d_in[5];
    const float* proj_b = (const float*)d_in[6];
    const float* relTab = (const float*)d_in[7];
    const float* n2g    = (const float*)d_in[8];
    const float* n2b    = (const float*)d_in[9];
    const float* w1     = (const float*)d_in[10];
    const float* b1     = (const float*)d_in[11];
    const float* w2     = (const float*)d_in[12];
    const float* b2     = (const float*)d_in[13];
    float* out = (float*)d_out;

    char* ws = (char*)d_ws;
    unsigned short* qkvT  = (unsigned short*)(ws);            // [576][192] bf16
    unsigned short* projT = (unsigned short*)(ws + 221184);   // [192][192] bf16
    unsigned short* w1T   = (unsigned short*)(ws + 294912);   // [384][192] bf16
    unsigned short* w2T   = (unsigned short*)(ws + 442368);   // [192][384] bf16
    float*          biasT = (float*)(ws + 589824);            // [6][64][64] f32

    k_prep<<<1248, 256, 0, stream>>>(qkv_w, proj_w, w1, w2, relTab, qkvT, projT, w1T, w2T, biasT);
    k_fused<<<2048, 512, 0, stream>>>(x, n1g, n1b, qkvT, qkv_b, projT, proj_b, biasT,
                                      n2g, n2b, w1T, b1, w2T, b2, out);
}

// Round 14
// 279.063 us; speedup vs baseline: 1.5765x; 1.3611x over previous
//
#include <hip/hip_runtime.h>
#include <hip/hip_bf16.h>

#define CC 192

typedef __attribute__((ext_vector_type(8))) short bf16x8;
typedef __attribute__((ext_vector_type(4))) float f32x4;

__device__ __forceinline__ unsigned short f2bf(float f) {
    unsigned int u = __float_as_uint(f);
    u = (u + 0x7fffu + ((u >> 16) & 1u)) >> 16;
    return (unsigned short)u;
}

__device__ __forceinline__ float bf2f(unsigned short u) {
    return __uint_as_float(((unsigned int)u) << 16);
}

__device__ __forceinline__ f32x4 mfma16(bf16x8 a, bf16x8 b, f32x4 c) {
    return __builtin_amdgcn_mfma_f32_16x16x32_bf16(a, b, c, 0, 0, 0);
}

// Merged prep: 4 weight transposes (f32 [K][N] -> bf16 [N][K]) + 4-class masked bias table.
__global__ void k_prep(const float* __restrict__ qkv_w, const float* __restrict__ proj_w,
                       const float* __restrict__ w1, const float* __restrict__ w2,
                       const float* __restrict__ relTab,
                       unsigned short* __restrict__ qkvT, unsigned short* __restrict__ projT,
                       unsigned short* __restrict__ w1T, unsigned short* __restrict__ w2T,
                       unsigned short* __restrict__ biasT4) {
    int idx = blockIdx.x * blockDim.x + threadIdx.x;
    if (idx < 110592) { int n = idx / 192, k = idx % 192; qkvT[idx] = f2bf(qkv_w[k * 576 + n]); return; }
    idx -= 110592;
    if (idx < 36864)  { int n = idx / 192, k = idx % 192; projT[idx] = f2bf(proj_w[k * 192 + n]); return; }
    idx -= 36864;
    if (idx < 73728)  { int n = idx / 192, k = idx % 192; w1T[idx] = f2bf(w1[k * 384 + n]); return; }
    idx -= 73728;
    if (idx < 73728)  { int n = idx / 384, k = idx % 384; w2T[idx] = f2bf(w2[k * 192 + n]); return; }
    idx -= 73728;
    if (idx < 98304) {   // [cls][h][i][j]: cls = (edgeH?2:0)+(edgeW?1:0); shift mask pre-added
        const int cls = idx / 24576, rem = idx % 24576;
        const int h = rem >> 12, i = (rem >> 6) & 63, j = rem & 63;
        const int yi = i >> 3, xi = i & 7, yj = j >> 3, xj = j & 7;
        const int rel = (yi - yj + 7) * 15 + (xi - xj + 7);
        float v = relTab[rel * 6 + h];
        const int bH = cls >> 1, bW = cls & 1;
        const int idi = (bH ? (yi >= 4 ? 2 : 1) : 0) * 3 + (bW ? (xi >= 4 ? 2 : 1) : 0);
        const int idj = (bH ? (yj >= 4 ? 2 : 1) : 0) * 3 + (bW ? (xj >= 4 ? 2 : 1) : 0);
        if (idi != idj) v -= 100.f;   // exp(-100+O(1)) flushes to 0 in f32, exact mask semantics
        biasT4[idx] = f2bf(v);
    }
}

// FUSED Swin block: one window per block (2048 blocks), 12 waves (768 threads).
// R9-proven structure (VGPR 68, no spill). LDS regions by phase lifetime:
//   rA [0,24K):   A (swz [64][192]) -> VT (swz [6][32][64]) -> AO -> A2
//   rQ [24K,48K): Q (swz [6][64][32]) -> P low half -> h-bf16 (swz [64][192])
//   rK [48K,72K): K (swz [6][64][32]) -> P high half -> G-half (swz [64][192], MLP two-pass)
// h is kept ONLY in LDS (bf16); `out` is written exactly once at the end.
__global__ __launch_bounds__(768, 3) void k_fused(
    const float* __restrict__ x,
    const float* __restrict__ n1g, const float* __restrict__ n1b,
    const unsigned short* __restrict__ qkvT, const float* __restrict__ qkv_b,
    const unsigned short* __restrict__ projT, const float* __restrict__ proj_b,
    const unsigned short* __restrict__ biasT4,
    const float* __restrict__ n2g, const float* __restrict__ n2b,
    const unsigned short* __restrict__ w1T, const float* __restrict__ b1,
    const unsigned short* __restrict__ w2T, const float* __restrict__ b2,
    float* __restrict__ out)
{
    __shared__ __align__(16) char smem[73728];
    __shared__ int sOpos[64];
    char* const rA = smem;
    char* const rQ = smem + 24576;
    char* const rK = smem + 49152;

    const int tid = threadIdx.x;
    const int wid = blockIdx.x;
    const int b = wid >> 6;
    const int win = wid & 63;
    const int wh = win >> 3, ww = win & 7;
    const int lane = tid & 63;
    const int wave = tid >> 6;
    const int lhi = lane >> 4, llo = lane & 15;

    // ---------- Phase 1: LN1 + shifted window gather (512 threads, 8/token) ----------
    if (tid < 512) {
        const int tok = tid >> 3;
        const int ch0 = (tid & 7) * 24;
        const int yi = tok >> 3, xi = tok & 7;
        const int oy = (wh * 8 + yi + 4) & 63;
        const int ox = (ww * 8 + xi + 4) & 63;
        const int base = ((b * 64 + oy) * 64 + ox) * CC;
        if ((tid & 7) == 0) sOpos[tok] = base;
        float v[24];
        float s = 0.f, ss = 0.f;
        #pragma unroll
        for (int i = 0; i < 6; ++i) {
            const float4 f = *(const float4*)(x + base + ch0 + i * 4);
            v[i*4+0]=f.x; v[i*4+1]=f.y; v[i*4+2]=f.z; v[i*4+3]=f.w;
            s  += f.x + f.y + f.z + f.w;
            ss += f.x*f.x + f.y*f.y + f.z*f.z + f.w*f.w;
        }
        s  += __shfl_xor(s, 1);  s  += __shfl_xor(s, 2);  s  += __shfl_xor(s, 4);
        ss += __shfl_xor(ss, 1); ss += __shfl_xor(ss, 2); ss += __shfl_xor(ss, 4);
        const float mean = s * (1.f / 192.f);
        const float rstd = rsqrtf(ss * (1.f / 192.f) - mean * mean + 1e-5f);
        char* aBase = rA + tok * 384;
        const int sw = (tok & 7) << 4;
        #pragma unroll
        for (int i = 0; i < 12; ++i) {
            const int c = ch0 + i * 2;
            const float a0 = (v[i*2+0] - mean) * rstd * n1g[c]   + n1b[c];
            const float a1 = (v[i*2+1] - mean) * rstd * n1g[c+1] + n1b[c+1];
            *(unsigned int*)(aBase + ((c * 2) ^ sw)) =
                (unsigned int)f2bf(a0) | ((unsigned int)f2bf(a1) << 16);
        }
    }
    __syncthreads();   // bar1: A ready

    // ---------- Phase 2: QKV GEMM, wave w -> cols [48w, 48w+48) ----------
    {
        const int cbase = wave * 48;
        f32x4 acc[4][3] = {};
        #pragma unroll
        for (int ks = 0; ks < 6; ++ks) {
            bf16x8 af[4];
            const int kbyte = ks * 64 + lhi * 16;
            #pragma unroll
            for (int m = 0; m < 4; ++m) {
                const int row = m * 16 + llo;
                af[m] = *(const bf16x8*)(rA + row * 384 + (kbyte ^ ((row & 7) << 4)));
            }
            #pragma unroll
            for (int n = 0; n < 3; ++n) {
                const int col = cbase + n * 16 + llo;
                const bf16x8 bfr = *(const bf16x8*)(qkvT + col * 192 + ks * 32 + lhi * 8);
                #pragma unroll
                for (int m = 0; m < 4; ++m) acc[m][n] = mfma16(af[m], bfr, acc[m][n]);
            }
        }
        __syncthreads();   // bar2: A fully consumed; rA region free for VT
        // epilogue: +bias, scatter to Q/K/VT LDS (SCALE folded into Q)
        #pragma unroll
        for (int n = 0; n < 3; ++n) {
            const int c0 = cbase + n * 16;
            const int which = c0 / 192;
            const int rem = c0 - which * 192;
            const int h = rem >> 5;
            const int d = (rem & 31) + llo;
            const float bia = qkv_b[c0 + llo];
            #pragma unroll
            for (int m = 0; m < 4; ++m) {
                #pragma unroll
                for (int r = 0; r < 4; ++r) {
                    const int row = m * 16 + lhi * 4 + r;
                    if (which == 0)
                        *(unsigned short*)(rQ + h * 4096 + row * 64 + ((2 * d) ^ ((row & 3) << 4)))
                            = f2bf((acc[m][n][r] + bia) * 0.17677669529663687f);
                    else if (which == 1)
                        *(unsigned short*)(rK + h * 4096 + row * 64 + ((2 * d) ^ ((row & 3) << 4)))
                            = f2bf(acc[m][n][r] + bia);
                    else
                        *(unsigned short*)(rA + h * 4096 + d * 128 + ((2 * row) ^ ((d & 7) << 4)))
                            = f2bf(acc[m][n][r] + bia);
                }
            }
        }
    }
    __syncthreads();   // bar3: Q/K/VT visible

    // ---------- Phase 3: attention (head = wave>>1, row-half = wave&1) ----------
    const int h = wave >> 1;
    const int mh = wave & 1;
    f32x4 pacc[2][2] = {};
    float rinv[2][4];
    {
        bf16x8 qf[2], kf[4];
        #pragma unroll
        for (int m = 0; m < 2; ++m) {
            const int t = (mh * 2 + m) * 16 + llo;
            qf[m] = *(const bf16x8*)(rQ + h * 4096 + t * 64 + ((lhi * 16) ^ ((t & 3) << 4)));
        }
        #pragma unroll
        for (int n = 0; n < 4; ++n) {
            const int t = n * 16 + llo;
            kf[n] = *(const bf16x8*)(rK + h * 4096 + t * 64 + ((lhi * 16) ^ ((t & 3) << 4)));
        }
        __syncthreads();   // bar4: Q/K in registers everywhere; rQ+rK free for P

        f32x4 sacc[2][4] = {};
        #pragma unroll
        for (int m = 0; m < 2; ++m)
            #pragma unroll
            for (int n = 0; n < 4; ++n)
                sacc[m][n] = mfma16(qf[m], kf[n], sacc[m][n]);

        // 4-class premasked bias table: no branch, no idi/idj math
        const int cls = ((wh == 7) ? 2 : 0) + ((ww == 7) ? 1 : 0);
        const unsigned short* bT = biasT4 + cls * 24576 + h * 4096;
        // no-max softmax (scores O(1), f32-exp exact)
        #pragma unroll
        for (int m = 0; m < 2; ++m) {
            #pragma unroll
            for (int r = 0; r < 4; ++r) {
                const int i = (mh * 2 + m) * 16 + lhi * 4 + r;
                float sum = 0.f;
                unsigned short pb[4];
                #pragma unroll
                for (int n = 0; n < 4; ++n) {
                    const int j = n * 16 + llo;
                    const float e = __expf(sacc[m][n][r] + bf2f(bT[i * 64 + j]));
                    sum += e;
                    pb[n] = f2bf(e);
                }
                sum += __shfl_xor(sum, 1);
                sum += __shfl_xor(sum, 2);
                sum += __shfl_xor(sum, 4);
                sum += __shfl_xor(sum, 8);
                rinv[m][r] = 1.f / sum;
                #pragma unroll
                for (int n = 0; n < 4; ++n) {
                    const int j = n * 16 + llo;
                    *(unsigned short*)(rQ + h * 8192 + i * 128 + ((2 * j) ^ ((i & 7) << 4))) = pb[n];
                }
            }
        }
        // P is wave-private (own 32 rows) -> no barrier before PV.
        #pragma unroll
        for (int ks = 0; ks < 2; ++ks) {
            bf16x8 pf[2];
            #pragma unroll
            for (int m = 0; m < 2; ++m) {
                const int t = (mh * 2 + m) * 16 + llo;
                pf[m] = *(const bf16x8*)(rQ + h * 8192 + t * 128 + ((ks * 64 + lhi * 16) ^ ((t & 7) << 4)));
            }
            #pragma unroll
            for (int n = 0; n < 2; ++n) {
                const int d = n * 16 + llo;
                const bf16x8 vf = *(const bf16x8*)(rA + h * 4096 + d * 128 + ((ks * 64 + lhi * 16) ^ ((d & 7) << 4)));
                #pragma unroll
                for (int m = 0; m < 2; ++m) pacc[m][n] = mfma16(pf[m], vf, pacc[m][n]);
            }
        }
    }
    __syncthreads();   // bar5: all VT/P reads done; rA free for AO
    {
        #pragma unroll
        for (int m = 0; m < 2; ++m) {
            #pragma unroll
            for (int n = 0; n < 2; ++n) {
                const int c = h * 32 + n * 16 + llo;
                #pragma unroll
                for (int r = 0; r < 4; ++r) {
                    const int i = (mh * 2 + m) * 16 + lhi * 4 + r;
                    *(unsigned short*)(rA + i * 384 + ((c * 2) ^ ((i & 7) << 4)))
                        = f2bf(pacc[m][n][r] * rinv[m][r]);
                }
            }
        }
    }
    __syncthreads();   // bar6: AO ready

    // ---------- Phase 4: proj GEMM + residual -> h (bf16) kept in LDS at rQ ----------
    {
        const int cbase = wave * 16;
        f32x4 acc[4] = {};
        #pragma unroll
        for (int ks = 0; ks < 6; ++ks) {
            bf16x8 af[4];
            const int kbyte = ks * 64 + lhi * 16;
            #pragma unroll
            for (int m = 0; m < 4; ++m) {
                const int row = m * 16 + llo;
                af[m] = *(const bf16x8*)(rA + row * 384 + (kbyte ^ ((row & 7) << 4)));
            }
            const int col = cbase + llo;
            const bf16x8 bfr = *(const bf16x8*)(projT + col * 192 + ks * 32 + lhi * 8);
            #pragma unroll
            for (int m = 0; m < 4; ++m) acc[m] = mfma16(af[m], bfr, acc[m]);
        }
        const int c = cbase + llo;
        const float pb = proj_b[c];
        #pragma unroll
        for (int m = 0; m < 4; ++m) {
            #pragma unroll
            for (int r = 0; r < 4; ++r) {
                const int i = m * 16 + lhi * 4 + r;
                const float hv = x[sOpos[i] + c] + acc[m][r] + pb;
                *(unsigned short*)(rQ + i * 384 + ((2 * c) ^ ((i & 7) << 4))) = f2bf(hv);
            }
        }
    }
    __syncthreads();   // bar7: h-bf16 visible in rQ

    // ---------- Phase 5: LN2 from LDS h -> A2 at rA ----------
    if (tid < 512) {
        const int tok = tid >> 3;
        const int ch0 = (tid & 7) * 24;
        const int sw = (tok & 7) << 4;
        float v[24]; float s = 0.f, ss = 0.f;
        #pragma unroll
        for (int i = 0; i < 12; ++i) {
            const int c = ch0 + i * 2;
            const unsigned uu = *(const unsigned*)(rQ + tok * 384 + ((2 * c) ^ sw));
            const float a0 = bf2f((unsigned short)uu);
            const float a1 = bf2f((unsigned short)(uu >> 16));
            v[2*i] = a0; v[2*i+1] = a1;
            s += a0 + a1;
            ss += a0 * a0 + a1 * a1;
        }
        s  += __shfl_xor(s, 1);  s  += __shfl_xor(s, 2);  s  += __shfl_xor(s, 4);
        ss += __shfl_xor(ss, 1); ss += __shfl_xor(ss, 2); ss += __shfl_xor(ss, 4);
        const float mean = s * (1.f / 192.f);
        const float rstd = rsqrtf(ss * (1.f / 192.f) - mean * mean + 1e-5f);
        char* aBase = rA + tok * 384;
        #pragma unroll
        for (int i = 0; i < 12; ++i) {
            const int c = ch0 + i * 2;
            const float a0 = (v[i*2]   - mean) * rstd * n2g[c]   + n2b[c];
            const float a1 = (v[i*2+1] - mean) * rstd * n2g[c+1] + n2b[c+1];
            *(unsigned int*)(aBase + ((c * 2) ^ sw)) =
                (unsigned int)f2bf(a0) | ((unsigned int)f2bf(a1) << 16);
        }
    }
    __syncthreads();   // bar8: A2 ready; rK free for G-half

    // ---------- Phase 6: MLP in two hidden halves; G-half [64][192] at rK ----------
    f32x4 accM[4] = {};
    #pragma unroll
    for (int hh = 0; hh < 2; ++hh) {
        // GEMM1 half: cols [hh*192 + 16w, +16), fast exact-enough GELU -> G-half
        {
            f32x4 a1[4] = {};
            #pragma unroll
            for (int ks = 0; ks < 6; ++ks) {
                bf16x8 af[4];
                const int kbyte = ks * 64 + lhi * 16;
                #pragma unroll
                for (int m = 0; m < 4; ++m) {
                    const int row = m * 16 + llo;
                    af[m] = *(const bf16x8*)(rA + row * 384 + (kbyte ^ ((row & 7) << 4)));
                }
                const bf16x8 bfr = *(const bf16x8*)(w1T + (hh * 192 + wave * 16 + llo) * 192 + ks * 32 + lhi * 8);
                #pragma unroll
                for (int m = 0; m < 4; ++m) a1[m] = mfma16(af[m], bfr, a1[m]);
            }
            const int cl = wave * 16 + llo;
            const float bb = b1[hh * 192 + cl];
            #pragma unroll
            for (int m = 0; m < 4; ++m) {
                #pragma unroll
                for (int r = 0; r < 4; ++r) {
                    const int i = m * 16 + lhi * 4 + r;
                    const float u = a1[m][r] + bb;
                    // gelu_tanh: 0.5u(1+tanh(k(u+0.044715u^3))) == u / (1 + e^{-2k(u+...)})
                    const float xx = 1.5957691216057308f * (u + 0.044715f * u * u * u);  // 2k
                    const float g = u / (1.f + __expf(-xx));
                    *(unsigned short*)(rK + i * 384 + ((2 * cl) ^ ((i & 7) << 4))) = f2bf(g);
                }
            }
        }
        __syncthreads();   // G-half ready
        // GEMM2 partial: K = [hh*192,+192), wave -> out cols [16w,+16)
        {
            #pragma unroll
            for (int ks = 0; ks < 6; ++ks) {
                bf16x8 af[4];
                const int kbyte = ks * 64 + lhi * 16;
                #pragma unroll
                for (int m = 0; m < 4; ++m) {
                    const int row = m * 16 + llo;
                    af[m] = *(const bf16x8*)(rK + row * 384 + (kbyte ^ ((row & 7) << 4)));
                }
                const bf16x8 bfr = *(const bf16x8*)(w2T + (wave * 16 + llo) * 384 + hh * 192 + ks * 32 + lhi * 8);
                #pragma unroll
                for (int m = 0; m < 4; ++m) accM[m] = mfma16(af[m], bfr, accM[m]);
            }
        }
        __syncthreads();   // G-half consumed (safe to overwrite)
    }
    // ---------- final: out = h + mlp (single global write) ----------
    {
        const int c = wave * 16 + llo;
        const float bb = b2[c];
        #pragma unroll
        for (int m = 0; m < 4; ++m) {
            #pragma unroll
            for (int r = 0; r < 4; ++r) {
                const int i = m * 16 + lhi * 4 + r;
                const float hv = bf2f(*(const unsigned short*)(rQ + i * 384 + ((2 * c) ^ ((i & 7) << 4))));
                out[sOpos[i] + c] = hv + accM[m][r] + bb;
            }
        }
    }
}

extern "C" void kernel_launch(void* const* d_in, const int* in_sizes, int n_in,
                              void* d_out, int out_size, void* d_ws, size_t ws_size,
                              hipStream_t stream)
{
    const float* x      = (const float*)d_in[0];
    const float* n1g    = (const float*)d_in[1];
    const float* n1b    = (const float*)d_in[2];
    const float* qkv_w  = (const float*)d_in[3];
    const float* qkv_b  = (const float*)d_in[4];
    const float* proj_w = (const float*)d_in[5];
    const float* proj_b = (const float*)d_in[6];
    const float* relTab = (const float*)d_in[7];
    const float* n2g    = (const float*)d_in[8];
    const float* n2b    = (const float*)d_in[9];
    const float* w1     = (const float*)d_in[10];
    const float* b1     = (const float*)d_in[11];
    const float* w2     = (const float*)d_in[12];
    const float* b2     = (const float*)d_in[13];
    float* out = (float*)d_out;

    char* ws = (char*)d_ws;
    unsigned short* qkvT   = (unsigned short*)(ws);            // [576][192] bf16
    unsigned short* projT  = (unsigned short*)(ws + 221184);   // [192][192] bf16
    unsigned short* w1T    = (unsigned short*)(ws + 294912);   // [384][192] bf16
    unsigned short* w2T    = (unsigned short*)(ws + 442368);   // [192][384] bf16
    unsigned short* biasT4 = (unsigned short*)(ws + 589824);   // [4][6][64][64] bf16 (masked)

    k_prep<<<1536, 256, 0, stream>>>(qkv_w, proj_w, w1, w2, relTab, qkvT, projT, w1T, w2T, biasT4);
    k_fused<<<2048, 768, 0, stream>>>(x, n1g, n1b, qkvT, qkv_b, projT, proj_b, biasT4,
                                      n2g, n2b, w1T, b1, w2T, b2, out);
}